// Round 20
// baseline (277.937 us; speedup 1.0000x reference)
//
#include <hip/hip_runtime.h>
#include <hip/hip_bf16.h>
#include <hip/hip_fp16.h>
#include <cstdint>
#include <cstddef>

#define H 256
#define L 128
#define B 512
#define LEVELS 7
#define BH (B * H) // 131072

// d_out layout (flat f32 element offsets), return order:
// root[B,H], internal_states[255,B,H], internal_mask[255,B],
// leaves[L,B,H], leaves_aux[L,B,H], leaves_mask[L,B]
#define OFF_ROOT 0
#define OFF_INT (B * H)
#define OFF_IMASK (OFF_INT + 255 * BH)
#define OFF_LEAVES (OFF_IMASK + 255 * B)
#define OFF_LAUX (OFF_LEAVES + L * BH)
#define OFF_LMASK (OFF_LAUX + L * BH)

typedef unsigned short u16;
typedef __attribute__((ext_vector_type(8))) _Float16 half8;
typedef __attribute__((ext_vector_type(4))) float f32x4;
typedef __attribute__((ext_vector_type(4))) u16 u16x4;
typedef __attribute__((ext_vector_type(16))) float f32x16;

#if __has_builtin(__builtin_amdgcn_exp2f)
#define EXP2(x) __builtin_amdgcn_exp2f(x)
#else
#define EXP2(x) exp2f(x)
#endif
#if __has_builtin(__builtin_amdgcn_rcpf)
#define RCP(x) __builtin_amdgcn_rcpf(x)
#else
#define RCP(x) (1.0f / (x))
#endif

// fast gates: |rel err| ~1e-7, negligible vs fp16 input rounding
__device__ __forceinline__ float fsigm(float x) {
    return RCP(1.0f + EXP2(-1.442695041f * x));
}
__device__ __forceinline__ float ftanh(float x) {
    return 1.0f - 2.0f * RCP(1.0f + EXP2(2.885390082f * x));
}

// Fragment-major h-plane layout (fp16, per node, B x H):
// tile T = (b>>5)*16 + (hc>>4); lane = (b&31) + 32*((hc>>3)&1); elem = hc&7
// u16 off = T*512 + lane*8 + elem  -> 32x32x16 A-frag = 1 reg load.
// Fragment-major c layout (fp16, per node): u16 off =
//   (((b>>5)*8 + (hc>>5))*8 + (lane>>5)*4 + q)*128 + (lane&31)*4 + e

__device__ __forceinline__ int postorder_pos(int level, int j) {
    int start = 0;
    for (int k = level; k <= LEVELS; ++k) {
        if ((j >> (k - level)) & 1) start += (2 << k) - 1;
    }
    return start + (2 << level) - 2;
}

__device__ __forceinline__ u16 f2h(float x) {
    _Float16 h = (_Float16)x;
    u16 u;
    __builtin_memcpy(&u, &h, 2);
    return u;
}
__device__ __forceinline__ float h2f(u16 u) {
    _Float16 h;
    __builtin_memcpy(&h, &u, 2);
    return (float)h;
}

__device__ __forceinline__ void gload16(const void* g, const void* l) {
    __builtin_amdgcn_global_load_lds(
        (const __attribute__((address_space(1))) void*)g,
        (__attribute__((address_space(3))) void*)l, 16, 0, 0);
}

// ---------------- gather: leaves, aux, level-0 post-order h, leaf planes ----
__global__ __launch_bounds__(256) void gather_kernel(
    const int* __restrict__ tok, const float* __restrict__ emb,
    const float* __restrict__ emb_aux, float* __restrict__ out,
    u16* __restrict__ spLeaf) {
    int row = blockIdx.x * 4 + (threadIdx.x >> 6);
    int f4i = threadIdx.x & 63;
    int l = row >> 9, b = row & 511;
    int t = tok[row];
    f32x4 e = *(reinterpret_cast<const f32x4*>(emb + (size_t)t * H) + f4i);
    f32x4 ea = *(reinterpret_cast<const f32x4*>(emb_aux + (size_t)t * H) + f4i);
    __builtin_nontemporal_store(
        e, reinterpret_cast<f32x4*>(out + OFF_LEAVES) + (size_t)row * 64 + f4i);
    __builtin_nontemporal_store(
        ea, reinterpret_cast<f32x4*>(out + OFF_LAUX) + (size_t)row * 64 + f4i);
    int pp = postorder_pos(0, l);
    __builtin_nontemporal_store(
        e, reinterpret_cast<f32x4*>(out + OFF_INT + (size_t)pp * BH +
                                    (size_t)b * H) +
               f4i);
    int ko = f4i >> 2;
    int lanep = (b & 31) + 32 * ((f4i >> 1) & 1);
    int elem0 = 4 * (f4i & 1);
    u16x4 hv;
    hv.x = f2h(e.x); hv.y = f2h(e.y); hv.z = f2h(e.z); hv.w = f2h(e.w);
    u16* np = spLeaf + (size_t)l * BH +
              (size_t)(((b >> 5) * 16 + ko) * 512 + lanep * 8 + elem0);
    *reinterpret_cast<u16x4*>(np) = hv;
}

// ---------------- W pre-pack into fragment-major fp16 tiles (+ masks, flags) -
__global__ __launch_bounds__(256) void wpack_kernel(const float* __restrict__ W,
                                                    u16* __restrict__ wp,
                                                    float* __restrict__ out,
                                                    int* __restrict__ flags) {
    int q = blockIdx.x * 256 + threadIdx.x; // 0 .. 655359, coalesced read
    int k = q / 1280, col = q - k * 1280;
    int gate = col >> 8, hc = col & 255;
    int hcb = hc >> 5, cl = hc & 31;
    int kb = k >> 5, klr = k & 31;
    int ks = klr >> 4, oct = (klr >> 3) & 1, elem = klr & 7;
    size_t off = ((size_t)(hcb * 16 + kb) * 10 + gate * 2 + ks) * 512 +
                 (cl + 32 * oct) * 8 + elem;
    wp[off] = f2h(W[q]);
    if (q < 255 * B) __builtin_nontemporal_store(1.0f, out + OFF_IMASK + q);
    if (q < L * B) __builtin_nontemporal_store(1.0f, out + OFF_LMASK + q);
    if (q < 64) flags[q] = 0; // dataflow counters, re-zeroed every call
}

// ---------------- shared per-unit GEMM + gate body (R13/R19-proven) ---------
// 2 waves. 4-deep counted-vmcnt pipeline, distance-2 W prefetch, single
// barrier per kb (slot rewritten 2 barriers after its last read, race-free).
__device__ __forceinline__ void run_unit(
    int lev, int p, int b0c, int hcb, const u16* __restrict__ wp,
    const float* __restrict__ bias, float* __restrict__ out,
    u16* __restrict__ spA, u16* __restrict__ cAll, u16 (*Wld)[10 * 512],
    int lane, int wm, int l31, int lh) {
    const int b0 = b0c * 128;
    const int hc0 = hcb * 32;
    const int cb = 256 - (256 >> (lev - 1)); // child node base
    const int nid = 256 - (256 >> lev) + p;

    const u16* sL = spA + (size_t)(cb + 2 * p) * BH;
    const u16* sR = sL + BH;

    f32x16 acc[2][5];
#pragma unroll
    for (int nf = 0; nf < 5; ++nf) {
        float bv = bias[nf * H + hc0 + l31];
        f32x16 v;
#pragma unroll
        for (int r = 0; r < 16; ++r) v[r] = bv;
        acc[0][nf] = v;
        acc[1][nf] = v;
    }

    half8 Af[4][2][2]; // [slot][mf][ks] — static indices (full unroll)

    auto stage = [&](int buf, int kb) {
        const u16* wsrc = wp + ((size_t)(hcb * 16 + kb) * 10) * 512;
#pragma unroll
        for (int i = 0; i < 5; ++i) {
            int t = 5 * wm + i;
            gload16(wsrc + t * 512 + lane * 8, &Wld[buf][t * 512]);
        }
        const u16* pl = (kb < 8) ? sL : sR;
#pragma unroll
        for (int mf = 0; mf < 2; ++mf)
#pragma unroll
            for (int ks = 0; ks < 2; ++ks) {
                int T = ((b0 >> 5) + 2 * wm + mf) * 16 + (kb & 7) * 2 + ks;
                Af[buf][mf][ks] = *reinterpret_cast<const half8*>(
                    pl + (size_t)T * 512 + lane * 8);
            }
    };

    stage(0, 0);
    stage(1, 1);
#pragma unroll
    for (int kb = 0; kb < 16; ++kb) {
        const int cur = kb & 3;
        if (kb < 14) {
            stage((kb + 2) & 3, kb + 2);
            // FIFO: 18 pending = kb+1/kb+2 stages; kb's loads complete.
            asm volatile("s_waitcnt vmcnt(18)" ::: "memory");
        } else if (kb == 14) {
            asm volatile("s_waitcnt vmcnt(9)" ::: "memory");
        } else {
            asm volatile("s_waitcnt vmcnt(0)" ::: "memory");
        }
        __builtin_amdgcn_s_barrier(); // kb W tiles visible to both waves
        __builtin_amdgcn_sched_barrier(0);
#pragma unroll
        for (int ks = 0; ks < 2; ++ks)
#pragma unroll
            for (int nf = 0; nf < 5; ++nf) {
                half8 bf = *reinterpret_cast<const half8*>(
                    &Wld[cur][(nf * 2 + ks) * 512 + lane * 8]);
                acc[0][nf] = __builtin_amdgcn_mfma_f32_32x32x16_f16(
                    Af[cur][0][ks], bf, acc[0][nf], 0, 0, 0);
                acc[1][nf] = __builtin_amdgcn_mfma_f32_32x32x16_f16(
                    Af[cur][1][ks], bf, acc[1][nf], 0, 0, 0);
            }
    }

    // ---- epilogue: gates -> c (fp16 frag), h (nt store) ----
    const int pout = postorder_pos(lev, p);
    float* __restrict__ hout = out + OFF_INT + (size_t)pout * BH;
    u16* __restrict__ cob = cAll + (size_t)(nid - 128) * BH;
    const u16* cLf =
        (lev >= 2) ? cAll + (size_t)(cb + 2 * p - 128) * BH : nullptr;
    const u16* cRf = cLf ? cLf + BH : nullptr;
    u16* __restrict__ soH = (lev < 7) ? spA + (size_t)nid * BH : nullptr;
    const int hc = hc0 + l31;
    const int kop = hcb * 2 + (l31 >> 4);
    const int lpp = 32 * ((l31 >> 3) & 1);
    const int elp = l31 & 7;

#pragma unroll
    for (int mf = 0; mf < 2; ++mf) {
        const int g = (b0 >> 5) + 2 * wm + mf;
        const size_t fbase =
            (((size_t)(g * 8 + hcb) * 8) + lh * 4) * 128 + l31 * 4;
#pragma unroll
        for (int q = 0; q < 4; ++q) {
            float cl4[4] = {0.f, 0.f, 0.f, 0.f};
            float cr4[4] = {0.f, 0.f, 0.f, 0.f};
            if (cLf) {
                u16x4 a = *reinterpret_cast<const u16x4*>(cLf + fbase + q * 128);
                u16x4 bq = *reinterpret_cast<const u16x4*>(cRf + fbase + q * 128);
                cl4[0] = h2f(a.x); cl4[1] = h2f(a.y);
                cl4[2] = h2f(a.z); cl4[3] = h2f(a.w);
                cr4[0] = h2f(bq.x); cr4[1] = h2f(bq.y);
                cr4[2] = h2f(bq.z); cr4[3] = h2f(bq.w);
            }
            u16x4 co4;
#pragma unroll
            for (int e = 0; e < 4; ++e) {
                const int r = 4 * q + e;
                float ig = acc[mf][0][r], f1 = acc[mf][1][r];
                float f2 = acc[mf][2][r], og = acc[mf][3][r];
                float ug = acc[mf][4][r];
                float c = fsigm(ig) * ftanh(ug) + fsigm(f1) * cl4[e] +
                          fsigm(f2) * cr4[e];
                float hval = fsigm(og) * ftanh(c);
                co4[e] = f2h(c);
                const int b = b0 + 64 * wm + 32 * mf + 4 * lh + e + 8 * q;
                __builtin_nontemporal_store(hval, hout + (size_t)b * H + hc);
                if (soH)
                    soH[(size_t)((b >> 5) * 16 + kop) * 512 +
                        (size_t)((b & 31) + lpp) * 8 + elp] = f2h(hval);
                if (lev == LEVELS)
                    __builtin_nontemporal_store(
                        hval, out + OFF_ROOT + (size_t)b * H + hc);
            }
            *reinterpret_cast<u16x4*>(cob + fbase + q * 128) = co4;
        }
    }
}

// ---------------- per-level LSTM kernel (levels 1..3) -----------------------
__global__ __launch_bounds__(128) void lstm_level(
    const u16* __restrict__ wp, const float* __restrict__ bias,
    float* __restrict__ out, u16* __restrict__ spA, u16* __restrict__ cAll,
    int lev) {
    __shared__ __align__(16) u16 Wld[4][10 * 512];
    const int tid = threadIdx.x;
    const int j = blockIdx.x;
    run_unit(lev, j >> 5, (j >> 3) & 3, j & 7, wp, bias, out, spA, cAll, Wld,
             tid & 63, tid >> 6, tid & 31 & 63, (tid & 63) >> 5);
}

// ---------------- fused tail kernel (levels 4..7, 480 blocks, dataflow) -----
// One unit per block; all 480 blocks co-resident (grid <= occupancy cap,
// verified host-side). Level 4 needs no waiting (children written by the
// level-3 launch). Levels 5-7 acquire per-(child-node, b0c) counters that
// level 4-6 units release (R8-verified primitive; flags distributed across
// 56 lines -> no contended spin line).
__global__ __launch_bounds__(128) void tree_tail(
    const u16* __restrict__ wp, const float* __restrict__ bias,
    float* __restrict__ out, u16* __restrict__ spA, u16* __restrict__ cAll,
    int* __restrict__ flags) {
    __shared__ __align__(16) u16 Wld[4][10 * 512];
    const int tid = threadIdx.x;
    const int lane = tid & 63;

    int u = blockIdx.x, lev, rem;
    if (u < 256)      { lev = 4; rem = u; }
    else if (u < 384) { lev = 5; rem = u - 256; }
    else if (u < 448) { lev = 6; rem = u - 384; }
    else              { lev = 7; rem = u - 448; }
    const int p = rem >> 5;
    const int b0c = (rem >> 3) & 3;
    const int hcb = rem & 7;

    if (lev >= 5) {
        const int cb = 256 - (256 >> (lev - 1)); // child base nid (>=240)
        const int f0 = (cb + 2 * p - 240) * 4 + b0c;
        while (__hip_atomic_load(&flags[f0], __ATOMIC_ACQUIRE,
                                 __HIP_MEMORY_SCOPE_AGENT) < 8 ||
               __hip_atomic_load(&flags[f0 + 4], __ATOMIC_ACQUIRE,
                                 __HIP_MEMORY_SCOPE_AGENT) < 8)
            __builtin_amdgcn_s_sleep(4);
    }

    run_unit(lev, p, b0c, hcb, wp, bias, out, spA, cAll, Wld, lane, tid >> 6,
             lane & 31, lane >> 5);

    if (lev < 7) {
        const int nid = 256 - (256 >> lev) + p;
        __threadfence();
        __syncthreads();
        if (tid == 0)
            __hip_atomic_fetch_add(&flags[(nid - 240) * 4 + b0c], 1,
                                   __ATOMIC_RELEASE,
                                   __HIP_MEMORY_SCOPE_AGENT);
    }
}

extern "C" void kernel_launch(void* const* d_in, const int* in_sizes, int n_in,
                              void* d_out, int out_size, void* d_ws,
                              size_t ws_size, hipStream_t stream) {
    const int* tok = (const int*)d_in[0];
    const float* emb = (const float*)d_in[1];
    const float* emb_aux = (const float*)d_in[2];
    const float* W = (const float*)d_in[3];
    const float* bias = (const float*)d_in[4];
    float* out = (float*)d_out;

    // ws: wp (1.31MB) | spA 254 fp16 planes (66.6MB) | cAll 127 fp16 frag
    // slabs (33.3MB) | flags (256B). All written before read every call.
    u16* wp = (u16*)d_ws;
    u16* spA = wp + (size_t)655360;
    u16* cAll = spA + (size_t)254 * BH;
    int* flags = (int*)(cAll + (size_t)127 * BH);

    hipLaunchKernelGGL(wpack_kernel, dim3(2560), dim3(256), 0, stream, W, wp,
                       out, flags);
    hipLaunchKernelGGL(gather_kernel, dim3(L * B / 4), dim3(256), 0, stream,
                       tok, emb, emb_aux, out, spA);

    for (int level = 1; level <= 3; ++level) {
        int units = 32 * (L >> level);
        hipLaunchKernelGGL(lstm_level, dim3(units), dim3(128), 0, stream, wp,
                           bias, out, spA, cAll, level);
    }

    int maxb = 0, ncu = 256, dev = 0;
    (void)hipGetDevice(&dev);
    (void)hipDeviceGetAttribute(&ncu, hipDeviceAttributeMultiprocessorCount,
                                dev);
    (void)hipOccupancyMaxActiveBlocksPerMultiprocessor(&maxb, tree_tail, 128,
                                                       0);
    if (maxb * ncu >= 480) {
        hipLaunchKernelGGL(tree_tail, dim3(480), dim3(128), 0, stream, wp,
                           bias, out, spA, cAll, flags);
    } else {
        for (int level = 4; level <= LEVELS; ++level) {
            int units = 32 * (L >> level);
            hipLaunchKernelGGL(lstm_level, dim3(units), dim3(128), 0, stream,
                               wp, bias, out, spA, cAll, level);
        }
    }
}

// Round 21
// 261.536 us; speedup vs baseline: 1.0627x; 1.0627x over previous
//
#include <hip/hip_runtime.h>
#include <hip/hip_bf16.h>
#include <hip/hip_fp16.h>
#include <cstdint>
#include <cstddef>

#define H 256
#define L 128
#define B 512
#define LEVELS 7
#define BH (B * H) // 131072

// d_out layout (flat f32 element offsets), return order:
// root[B,H], internal_states[255,B,H], internal_mask[255,B],
// leaves[L,B,H], leaves_aux[L,B,H], leaves_mask[L,B]
#define OFF_ROOT 0
#define OFF_INT (B * H)
#define OFF_IMASK (OFF_INT + 255 * BH)
#define OFF_LEAVES (OFF_IMASK + 255 * B)
#define OFF_LAUX (OFF_LEAVES + L * BH)
#define OFF_LMASK (OFF_LAUX + L * BH)

typedef unsigned short u16;
typedef __attribute__((ext_vector_type(8))) _Float16 half8;
typedef __attribute__((ext_vector_type(4))) float f32x4;
typedef __attribute__((ext_vector_type(4))) u16 u16x4;
typedef __attribute__((ext_vector_type(16))) float f32x16;

#if __has_builtin(__builtin_amdgcn_exp2f)
#define EXP2(x) __builtin_amdgcn_exp2f(x)
#else
#define EXP2(x) exp2f(x)
#endif
#if __has_builtin(__builtin_amdgcn_rcpf)
#define RCP(x) __builtin_amdgcn_rcpf(x)
#else
#define RCP(x) (1.0f / (x))
#endif

// fast gates: |rel err| ~1e-7, negligible vs fp16 input rounding
__device__ __forceinline__ float fsigm(float x) {
    return RCP(1.0f + EXP2(-1.442695041f * x));
}
__device__ __forceinline__ float ftanh(float x) {
    return 1.0f - 2.0f * RCP(1.0f + EXP2(2.885390082f * x));
}

// Fragment-major h-plane layout (fp16, per node, B x H):
// tile T = (b>>5)*16 + (hc>>4); lane = (b&31) + 32*((hc>>3)&1); elem = hc&7
// u16 off = T*512 + lane*8 + elem  -> 32x32x16 A-frag = 1 reg load.
// Fragment-major c layout (fp16, per node): u16 off =
//   (((b>>5)*8 + (hc>>5))*8 + (lane>>5)*4 + q)*128 + (lane&31)*4 + e

__device__ __forceinline__ int postorder_pos(int level, int j) {
    int start = 0;
    for (int k = level; k <= LEVELS; ++k) {
        if ((j >> (k - level)) & 1) start += (2 << k) - 1;
    }
    return start + (2 << level) - 2;
}

__device__ __forceinline__ u16 f2h(float x) {
    _Float16 h = (_Float16)x;
    u16 u;
    __builtin_memcpy(&u, &h, 2);
    return u;
}
__device__ __forceinline__ float h2f(u16 u) {
    _Float16 h;
    __builtin_memcpy(&h, &u, 2);
    return (float)h;
}

__device__ __forceinline__ void gload16(const void* g, const void* l) {
    __builtin_amdgcn_global_load_lds(
        (const __attribute__((address_space(1))) void*)g,
        (__attribute__((address_space(3))) void*)l, 16, 0, 0);
}

// ---------------- gather: leaves, aux, level-0 post-order h, leaf planes ----
__global__ __launch_bounds__(256) void gather_kernel(
    const int* __restrict__ tok, const float* __restrict__ emb,
    const float* __restrict__ emb_aux, float* __restrict__ out,
    u16* __restrict__ spLeaf) {
    int row = blockIdx.x * 4 + (threadIdx.x >> 6);
    int f4i = threadIdx.x & 63;
    int l = row >> 9, b = row & 511;
    int t = tok[row];
    f32x4 e = *(reinterpret_cast<const f32x4*>(emb + (size_t)t * H) + f4i);
    f32x4 ea = *(reinterpret_cast<const f32x4*>(emb_aux + (size_t)t * H) + f4i);
    __builtin_nontemporal_store(
        e, reinterpret_cast<f32x4*>(out + OFF_LEAVES) + (size_t)row * 64 + f4i);
    __builtin_nontemporal_store(
        ea, reinterpret_cast<f32x4*>(out + OFF_LAUX) + (size_t)row * 64 + f4i);
    int pp = postorder_pos(0, l);
    __builtin_nontemporal_store(
        e, reinterpret_cast<f32x4*>(out + OFF_INT + (size_t)pp * BH +
                                    (size_t)b * H) +
               f4i);
    int ko = f4i >> 2;
    int lanep = (b & 31) + 32 * ((f4i >> 1) & 1);
    int elem0 = 4 * (f4i & 1);
    u16x4 hv;
    hv.x = f2h(e.x); hv.y = f2h(e.y); hv.z = f2h(e.z); hv.w = f2h(e.w);
    u16* np = spLeaf + (size_t)l * BH +
              (size_t)(((b >> 5) * 16 + ko) * 512 + lanep * 8 + elem0);
    *reinterpret_cast<u16x4*>(np) = hv;
}

// ---------------- W pre-pack into fragment-major fp16 tiles (+ masks, flags) -
__global__ __launch_bounds__(256) void wpack_kernel(const float* __restrict__ W,
                                                    u16* __restrict__ wp,
                                                    float* __restrict__ out,
                                                    int* __restrict__ flags) {
    int q = blockIdx.x * 256 + threadIdx.x; // 0 .. 655359, coalesced read
    int k = q / 1280, col = q - k * 1280;
    int gate = col >> 8, hc = col & 255;
    int hcb = hc >> 5, cl = hc & 31;
    int kb = k >> 5, klr = k & 31;
    int ks = klr >> 4, oct = (klr >> 3) & 1, elem = klr & 7;
    size_t off = ((size_t)(hcb * 16 + kb) * 10 + gate * 2 + ks) * 512 +
                 (cl + 32 * oct) * 8 + elem;
    wp[off] = f2h(W[q]);
    if (q < 255 * B) __builtin_nontemporal_store(1.0f, out + OFF_IMASK + q);
    if (q < L * B) __builtin_nontemporal_store(1.0f, out + OFF_LMASK + q);
    if (q < 64) flags[q] = 0; // dataflow counters, re-zeroed every call
}

// ---------------- shared per-unit GEMM + gate body (R13/R19-proven) ---------
// 2 waves. 4-deep counted-vmcnt pipeline, distance-2 W prefetch, single
// barrier per kb (slot rewritten 2 barriers after its last read, race-free).
__device__ __forceinline__ void run_unit(
    int lev, int p, int b0c, int hcb, const u16* __restrict__ wp,
    const float* __restrict__ bias, float* __restrict__ out,
    u16* __restrict__ spA, u16* __restrict__ cAll, u16 (*Wld)[10 * 512],
    int lane, int wm, int l31, int lh) {
    const int b0 = b0c * 128;
    const int hc0 = hcb * 32;
    const int cb = 256 - (256 >> (lev - 1)); // child node base
    const int nid = 256 - (256 >> lev) + p;

    const u16* sL = spA + (size_t)(cb + 2 * p) * BH;
    const u16* sR = sL + BH;

    f32x16 acc[2][5];
#pragma unroll
    for (int nf = 0; nf < 5; ++nf) {
        float bv = bias[nf * H + hc0 + l31];
        f32x16 v;
#pragma unroll
        for (int r = 0; r < 16; ++r) v[r] = bv;
        acc[0][nf] = v;
        acc[1][nf] = v;
    }

    half8 Af[4][2][2]; // [slot][mf][ks] — static indices (full unroll)

    auto stage = [&](int buf, int kb) {
        const u16* wsrc = wp + ((size_t)(hcb * 16 + kb) * 10) * 512;
#pragma unroll
        for (int i = 0; i < 5; ++i) {
            int t = 5 * wm + i;
            gload16(wsrc + t * 512 + lane * 8, &Wld[buf][t * 512]);
        }
        const u16* pl = (kb < 8) ? sL : sR;
#pragma unroll
        for (int mf = 0; mf < 2; ++mf)
#pragma unroll
            for (int ks = 0; ks < 2; ++ks) {
                int T = ((b0 >> 5) + 2 * wm + mf) * 16 + (kb & 7) * 2 + ks;
                Af[buf][mf][ks] = *reinterpret_cast<const half8*>(
                    pl + (size_t)T * 512 + lane * 8);
            }
    };

    stage(0, 0);
    stage(1, 1);
#pragma unroll
    for (int kb = 0; kb < 16; ++kb) {
        const int cur = kb & 3;
        if (kb < 14) {
            stage((kb + 2) & 3, kb + 2);
            // FIFO: 18 pending = kb+1/kb+2 stages; kb's loads complete.
            asm volatile("s_waitcnt vmcnt(18)" ::: "memory");
        } else if (kb == 14) {
            asm volatile("s_waitcnt vmcnt(9)" ::: "memory");
        } else {
            asm volatile("s_waitcnt vmcnt(0)" ::: "memory");
        }
        __builtin_amdgcn_s_barrier(); // kb W tiles visible to both waves
        __builtin_amdgcn_sched_barrier(0);
#pragma unroll
        for (int ks = 0; ks < 2; ++ks)
#pragma unroll
            for (int nf = 0; nf < 5; ++nf) {
                half8 bf = *reinterpret_cast<const half8*>(
                    &Wld[cur][(nf * 2 + ks) * 512 + lane * 8]);
                acc[0][nf] = __builtin_amdgcn_mfma_f32_32x32x16_f16(
                    Af[cur][0][ks], bf, acc[0][nf], 0, 0, 0);
                acc[1][nf] = __builtin_amdgcn_mfma_f32_32x32x16_f16(
                    Af[cur][1][ks], bf, acc[1][nf], 0, 0, 0);
            }
    }

    // ---- epilogue: gates -> c (fp16 frag), h (nt store) ----
    const int pout = postorder_pos(lev, p);
    float* __restrict__ hout = out + OFF_INT + (size_t)pout * BH;
    u16* __restrict__ cob = cAll + (size_t)(nid - 128) * BH;
    const u16* cLf =
        (lev >= 2) ? cAll + (size_t)(cb + 2 * p - 128) * BH : nullptr;
    const u16* cRf = cLf ? cLf + BH : nullptr;
    u16* __restrict__ soH = (lev < 7) ? spA + (size_t)nid * BH : nullptr;
    const int hc = hc0 + l31;
    const int kop = hcb * 2 + (l31 >> 4);
    const int lpp = 32 * ((l31 >> 3) & 1);
    const int elp = l31 & 7;

#pragma unroll
    for (int mf = 0; mf < 2; ++mf) {
        const int g = (b0 >> 5) + 2 * wm + mf;
        const size_t fbase =
            (((size_t)(g * 8 + hcb) * 8) + lh * 4) * 128 + l31 * 4;
#pragma unroll
        for (int q = 0; q < 4; ++q) {
            float cl4[4] = {0.f, 0.f, 0.f, 0.f};
            float cr4[4] = {0.f, 0.f, 0.f, 0.f};
            if (cLf) {
                u16x4 a = *reinterpret_cast<const u16x4*>(cLf + fbase + q * 128);
                u16x4 bq = *reinterpret_cast<const u16x4*>(cRf + fbase + q * 128);
                cl4[0] = h2f(a.x); cl4[1] = h2f(a.y);
                cl4[2] = h2f(a.z); cl4[3] = h2f(a.w);
                cr4[0] = h2f(bq.x); cr4[1] = h2f(bq.y);
                cr4[2] = h2f(bq.z); cr4[3] = h2f(bq.w);
            }
            u16x4 co4;
#pragma unroll
            for (int e = 0; e < 4; ++e) {
                const int r = 4 * q + e;
                float ig = acc[mf][0][r], f1 = acc[mf][1][r];
                float f2 = acc[mf][2][r], og = acc[mf][3][r];
                float ug = acc[mf][4][r];
                float c = fsigm(ig) * ftanh(ug) + fsigm(f1) * cl4[e] +
                          fsigm(f2) * cr4[e];
                float hval = fsigm(og) * ftanh(c);
                co4[e] = f2h(c);
                const int b = b0 + 64 * wm + 32 * mf + 4 * lh + e + 8 * q;
                __builtin_nontemporal_store(hval, hout + (size_t)b * H + hc);
                if (soH)
                    soH[(size_t)((b >> 5) * 16 + kop) * 512 +
                        (size_t)((b & 31) + lpp) * 8 + elp] = f2h(hval);
                if (lev == LEVELS)
                    __builtin_nontemporal_store(
                        hval, out + OFF_ROOT + (size_t)b * H + hc);
            }
            *reinterpret_cast<u16x4*>(cob + fbase + q * 128) = co4;
        }
    }
}

// ---------------- per-level LSTM kernel (levels 1..3) -----------------------
// Pair-major block map: pair = blockIdx % (4n), hcb = blockIdx / (4n).
// 4n % 8 == 0 -> the 8 hcb-units of one (p,b0c) have ids differing by
// multiples of 8 -> same XCD under round-robin -> the shared 128 KB child
// A-region is fetched into that XCD's L2 once (was: 8 XCDs, 8 fetches).
__global__ __launch_bounds__(128) void lstm_level(
    const u16* __restrict__ wp, const float* __restrict__ bias,
    float* __restrict__ out, u16* __restrict__ spA, u16* __restrict__ cAll,
    int lev) {
    __shared__ __align__(16) u16 Wld[4][10 * 512];
    const int tid = threadIdx.x;
    const int npair = gridDim.x >> 3; // = 4n
    const int pair = blockIdx.x % npair;
    const int hcb = blockIdx.x / npair;
    run_unit(lev, pair >> 2, pair & 3, hcb, wp, bias, out, spA, cAll, Wld,
             tid & 63, tid >> 6, tid & 31, (tid & 63) >> 5);
}

// ---------------- fused tail kernel (levels 4..7, 480 blocks, dataflow) -----
// Same pair-major remap within each level section (section bases are
// multiples of 8, so mod-8 classes survive). Flags logic uses (p,b0c) only,
// so the remap is sync-transparent.
__global__ __launch_bounds__(128) void tree_tail(
    const u16* __restrict__ wp, const float* __restrict__ bias,
    float* __restrict__ out, u16* __restrict__ spA, u16* __restrict__ cAll,
    int* __restrict__ flags) {
    __shared__ __align__(16) u16 Wld[4][10 * 512];
    const int tid = threadIdx.x;
    const int lane = tid & 63;

    int u = blockIdx.x, lev, rem, npair;
    if (u < 256)      { lev = 4; rem = u;       npair = 32; }
    else if (u < 384) { lev = 5; rem = u - 256; npair = 16; }
    else if (u < 448) { lev = 6; rem = u - 384; npair = 8; }
    else              { lev = 7; rem = u - 448; npair = 4; }
    const int pair = rem % npair;
    const int hcb = rem / npair;
    const int p = pair >> 2;
    const int b0c = pair & 3;

    if (lev >= 5) {
        const int cb = 256 - (256 >> (lev - 1)); // child base nid (>=240)
        const int f0 = (cb + 2 * p - 240) * 4 + b0c;
        while (__hip_atomic_load(&flags[f0], __ATOMIC_ACQUIRE,
                                 __HIP_MEMORY_SCOPE_AGENT) < 8 ||
               __hip_atomic_load(&flags[f0 + 4], __ATOMIC_ACQUIRE,
                                 __HIP_MEMORY_SCOPE_AGENT) < 8)
            __builtin_amdgcn_s_sleep(4);
    }

    run_unit(lev, p, b0c, hcb, wp, bias, out, spA, cAll, Wld, lane, tid >> 6,
             lane & 31, lane >> 5);

    if (lev < 7) {
        const int nid = 256 - (256 >> lev) + p;
        __threadfence();
        __syncthreads();
        if (tid == 0)
            __hip_atomic_fetch_add(&flags[(nid - 240) * 4 + b0c], 1,
                                   __ATOMIC_RELEASE,
                                   __HIP_MEMORY_SCOPE_AGENT);
    }
}

extern "C" void kernel_launch(void* const* d_in, const int* in_sizes, int n_in,
                              void* d_out, int out_size, void* d_ws,
                              size_t ws_size, hipStream_t stream) {
    const int* tok = (const int*)d_in[0];
    const float* emb = (const float*)d_in[1];
    const float* emb_aux = (const float*)d_in[2];
    const float* W = (const float*)d_in[3];
    const float* bias = (const float*)d_in[4];
    float* out = (float*)d_out;

    // ws: wp (1.31MB) | spA 254 fp16 planes (66.6MB) | cAll 127 fp16 frag
    // slabs (33.3MB) | flags (256B). All written before read every call.
    u16* wp = (u16*)d_ws;
    u16* spA = wp + (size_t)655360;
    u16* cAll = spA + (size_t)254 * BH;
    int* flags = (int*)(cAll + (size_t)127 * BH);

    hipLaunchKernelGGL(wpack_kernel, dim3(2560), dim3(256), 0, stream, W, wp,
                       out, flags);
    hipLaunchKernelGGL(gather_kernel, dim3(L * B / 4), dim3(256), 0, stream,
                       tok, emb, emb_aux, out, spA);

    for (int level = 1; level <= 3; ++level) {
        int units = 32 * (L >> level);
        hipLaunchKernelGGL(lstm_level, dim3(units), dim3(128), 0, stream, wp,
                           bias, out, spA, cAll, level);
    }

    int maxb = 0, ncu = 256, dev = 0;
    (void)hipGetDevice(&dev);
    (void)hipDeviceGetAttribute(&ncu, hipDeviceAttributeMultiprocessorCount,
                                dev);
    (void)hipOccupancyMaxActiveBlocksPerMultiprocessor(&maxb, tree_tail, 128,
                                                       0);
    if (maxb * ncu >= 480) {
        hipLaunchKernelGGL(tree_tail, dim3(480), dim3(128), 0, stream, wp,
                           bias, out, spA, cAll, flags);
    } else {
        for (int level = 4; level <= LEVELS; ++level) {
            int units = 32 * (L >> level);
            hipLaunchKernelGGL(lstm_level, dim3(units), dim3(128), 0, stream,
                               wp, bias, out, spA, cAll, level);
        }
    }
}